// Round 1
// baseline (548.118 us; speedup 1.0000x reference)
//
#include <hip/hip_runtime.h>
#include <hip/hip_bf16.h>

// LocalWindowAttention on MI355X, bf16 MFMA pipeline.
// Workspace layout (bytes):
//   x_bf16   @ 0          : 16384*1024*2 = 33,554,432
//   qkv      @ 33554432   : 16384*3072*2 = 100,663,296
//   attn_out @ 134217728  : 16384*1024*2 = 33,554,432
//   WqkvT    @ 167772160  : 3072*1024*2  = 6,291,456
//   WoutT    @ 174063616  : 1024*1024*2  = 2,097,152
//   total 176,160,768 bytes

typedef unsigned short u16;
typedef __bf16 bf16x8 __attribute__((ext_vector_type(8)));
typedef float f32x4 __attribute__((ext_vector_type(4)));

#define GLDS16(src, dst) \
  __builtin_amdgcn_global_load_lds((const __attribute__((address_space(1))) void*)(src), \
                                   (__attribute__((address_space(3))) void*)(dst), 16, 0, 0)

static __device__ __forceinline__ u16 f2bfu(float f) {
  union { __hip_bfloat16 b; u16 u; } cv;
  cv.b = __float2bfloat16(f);
  return cv.u;
}

// ---------------- x fp32 -> bf16 (vectorized) ----------------
__global__ __launch_bounds__(256) void cvt_x_kernel(const float* __restrict__ in,
                                                    u16* __restrict__ out, int n4) {
  int i = blockIdx.x * 256 + threadIdx.x;
  int stride = gridDim.x * 256;
  for (; i < n4; i += stride) {
    float4 v = reinterpret_cast<const float4*>(in)[i];
    ushort4 o;
    o.x = f2bfu(v.x); o.y = f2bfu(v.y); o.z = f2bfu(v.z); o.w = f2bfu(v.w);
    reinterpret_cast<ushort4*>(out)[i] = o;
  }
}

// ---------------- W [R][C] fp32 -> Wt [C][R] bf16 ----------------
__global__ __launch_bounds__(256) void transpose_cvt_kernel(const float* __restrict__ src,
                                                            u16* __restrict__ dst, int R, int C) {
  __shared__ float tile[32][33];
  int tilesR = R >> 5;
  int tr = blockIdx.x % tilesR;
  int tc = blockIdx.x / tilesR;
  int tx = threadIdx.x & 31, ty = threadIdx.x >> 5;  // ty 0..7
  #pragma unroll
  for (int i = 0; i < 4; ++i) {
    int r = (tr << 5) + ty + (i << 3);
    int c = (tc << 5) + tx;
    tile[ty + (i << 3)][tx] = src[(size_t)r * C + c];
  }
  __syncthreads();
  #pragma unroll
  for (int i = 0; i < 4; ++i) {
    int orow = (tc << 5) + ty + (i << 3);  // original col
    int ocol = (tr << 5) + tx;             // original row
    dst[(size_t)orow * R + ocol] = f2bfu(tile[tx][ty + (i << 3)]);
  }
}

// ---------------- m97-style 128x128 GEMM: C = A * Bt^T + bias ----------------
// A [M][K] bf16, Bt [N][K] bf16, C [M][N]. M multiple of 128 (bm = bid&127 hardcodes M=16384).
template <bool BF16OUT>
__global__ __launch_bounds__(256) void gemm_bt_kernel(const u16* __restrict__ A,
                                                      const u16* __restrict__ Bt,
                                                      const float* __restrict__ bias,
                                                      void* __restrict__ Cout,
                                                      int M, int N, int K) {
  __shared__ u16 lA[128 * 32];
  __shared__ u16 lB[128 * 32];
  int bid = blockIdx.x;
  int bm = bid & 127;  // M/128 == 128
  int bn = bid >> 7;
  int t = threadIdx.x;
  int w = t >> 6, l = t & 63, g = l >> 4, r16 = l & 15;
  int wr = w >> 1, wc = w & 1;

  f32x4 acc[4][4];
  #pragma unroll
  for (int mi = 0; mi < 4; ++mi)
    #pragma unroll
    for (int ni = 0; ni < 4; ++ni)
      acc[mi][ni] = f32x4{0.f, 0.f, 0.f, 0.f};

  const size_t arow0 = (size_t)bm * 128;
  const size_t brow0 = (size_t)bn * 128;
  int ra = t >> 2;   // 0..63 (row within half-tile)
  int ca = t & 3;    // 16B chunk within 64B row

  for (int kt = 0; kt < K; kt += 32) {
    __syncthreads();
    #pragma unroll
    for (int p = 0; p < 2; ++p) {
      GLDS16(A + (arow0 + ra + 64 * p) * K + kt + ca * 8, &lA[t * 8 + p * 2048]);
      GLDS16(Bt + (brow0 + ra + 64 * p) * K + kt + ca * 8, &lB[t * 8 + p * 2048]);
    }
    __syncthreads();
    bf16x8 af[4], bf[4];
    #pragma unroll
    for (int mi = 0; mi < 4; ++mi)
      af[mi] = *reinterpret_cast<const bf16x8*>(&lA[(wr * 64 + mi * 16 + r16) * 32 + g * 8]);
    #pragma unroll
    for (int ni = 0; ni < 4; ++ni)
      bf[ni] = *reinterpret_cast<const bf16x8*>(&lB[(wc * 64 + ni * 16 + r16) * 32 + g * 8]);
    #pragma unroll
    for (int mi = 0; mi < 4; ++mi)
      #pragma unroll
      for (int ni = 0; ni < 4; ++ni)
        acc[mi][ni] = __builtin_amdgcn_mfma_f32_16x16x32_bf16(af[mi], bf[ni], acc[mi][ni], 0, 0, 0);
  }

  #pragma unroll
  for (int ni = 0; ni < 4; ++ni) {
    int col = (bn * 128) + wc * 64 + ni * 16 + r16;
    float bv = bias[col];
    #pragma unroll
    for (int mi = 0; mi < 4; ++mi) {
      int rowb = (bm * 128) + wr * 64 + mi * 16 + g * 4;
      #pragma unroll
      for (int reg = 0; reg < 4; ++reg) {
        float v = acc[mi][ni][reg] + bv;
        if (BF16OUT)
          ((u16*)Cout)[(size_t)(rowb + reg) * N + col] = f2bfu(v);
        else
          ((float*)Cout)[(size_t)(rowb + reg) * N + col] = v;
      }
    }
  }
}

// ---------------- banded attention ----------------
// grid: 2048 blocks = (b:4, h:16, n:32). 256 threads = 4 waves, wave w owns q rows [32w, 32w+32).
// qkv [16384][3072] bf16 (cols: 0..1023 q | 1024..2047 k | 2048..3071 v), aout [16384][1024] bf16.
#define SCALE_LOG2 0.04508422002778011f  // log2(e) / 32  (scale = 1/sqrt(1024))

__global__ __launch_bounds__(256) void attn_kernel(const u16* __restrict__ qkv,
                                                   u16* __restrict__ aout) {
  __shared__ u16 vt[64 * 136];        // V^T [dh][key], pad 128->136 (272B rows, 16B aligned)
  __shared__ u16 plds[4 * 32 * 136];  // per-wave P [32 q][key]

  int bid = blockIdx.x;
  int n = bid & 31;
  int h = (bid >> 5) & 15;
  int b = bid >> 9;

  const int t = threadIdx.x;
  const int w = t >> 6, l = t & 63, g = l >> 4, r16 = l & 15;

  const size_t bs = (size_t)b * 4096;
  const u16* qsec = qkv + (bs + (size_t)n * 128) * 3072 + h * 64;

  // Q A-frags held in registers for the whole block
  bf16x8 qa[2][2];
  #pragma unroll
  for (int mf = 0; mf < 2; ++mf)
    #pragma unroll
    for (int ks = 0; ks < 2; ++ks)
      qa[mf][ks] = *reinterpret_cast<const bf16x8*>(
          qsec + (size_t)(w * 32 + mf * 16 + r16) * 3072 + ks * 32 + g * 8);

  f32x4 o[2][4];
  #pragma unroll
  for (int mf = 0; mf < 2; ++mf)
    #pragma unroll
    for (int ni = 0; ni < 4; ++ni)
      o[mf][ni] = f32x4{0.f, 0.f, 0.f, 0.f};
  float m_run[2][4], l_run[2][4];
  #pragma unroll
  for (int mf = 0; mf < 2; ++mf)
    #pragma unroll
    for (int reg = 0; reg < 4; ++reg) { m_run[mf][reg] = -3.0e38f; l_run[mf][reg] = 0.f; }

  for (int d = -1; d <= 1; ++d) {
    int kblk = n + d;
    if (kblk < 0 || kblk >= 32) continue;  // block-uniform
    const u16* ksec = qkv + (bs + (size_t)kblk * 128) * 3072 + 1024 + h * 64;
    const u16* vsec = ksec + 1024;

    __syncthreads();  // protect vt from previous iteration's PV reads
    // stage V^T: coalesced row reads, scattered b16 LDS writes
    #pragma unroll
    for (int p = 0; p < 4; ++p) {
      int key = (t >> 3) + 32 * p;
      int c = t & 7;
      uint4 pk = *reinterpret_cast<const uint4*>(vsec + (size_t)key * 3072 + c * 8);
      const u16* pv = reinterpret_cast<const u16*>(&pk);
      #pragma unroll
      for (int j = 0; j < 8; ++j)
        vt[(c * 8 + j) * 136 + key] = pv[j];
    }
    __syncthreads();

    // scores: S = Q K^T (raw, scale folded into exp2)
    f32x4 s[2][8];
    #pragma unroll
    for (int mf = 0; mf < 2; ++mf)
      #pragma unroll
      for (int nf = 0; nf < 8; ++nf)
        s[mf][nf] = f32x4{0.f, 0.f, 0.f, 0.f};
    #pragma unroll
    for (int nf = 0; nf < 8; ++nf) {
      #pragma unroll
      for (int ks = 0; ks < 2; ++ks) {
        bf16x8 kf = *reinterpret_cast<const bf16x8*>(
            ksec + (size_t)(nf * 16 + r16) * 3072 + ks * 32 + g * 8);
        #pragma unroll
        for (int mf = 0; mf < 2; ++mf)
          s[mf][nf] = __builtin_amdgcn_mfma_f32_16x16x32_bf16(qa[mf][ks], kf, s[mf][nf], 0, 0, 0);
      }
    }

    // triangular masks for the +-1 blocks: d=-1 valid j>=i; d=+1 valid j<=i
    if (d != 0) {
      #pragma unroll
      for (int mf = 0; mf < 2; ++mf)
        #pragma unroll
        for (int reg = 0; reg < 4; ++reg) {
          int i = w * 32 + mf * 16 + g * 4 + reg;
          #pragma unroll
          for (int nf = 0; nf < 8; ++nf) {
            int j = nf * 16 + r16;
            bool bad = (d < 0) ? (j < i) : (j > i);
            if (bad) s[mf][nf][reg] = -3.0e38f;
          }
        }
    }

    // online softmax per row (rows live in 16-lane groups; reduce via shfl_xor 1..8)
    #pragma unroll
    for (int mf = 0; mf < 2; ++mf)
      #pragma unroll
      for (int reg = 0; reg < 4; ++reg) {
        float bm2 = s[mf][0][reg];
        #pragma unroll
        for (int nf = 1; nf < 8; ++nf) bm2 = fmaxf(bm2, s[mf][nf][reg]);
        #pragma unroll
        for (int d2 = 1; d2 < 16; d2 <<= 1) bm2 = fmaxf(bm2, __shfl_xor(bm2, d2));
        float mo = m_run[mf][reg];
        float mn = fmaxf(mo, bm2);
        float sc = exp2f((mo - mn) * SCALE_LOG2);
        m_run[mf][reg] = mn;
        float rs = 0.f;
        #pragma unroll
        for (int nf = 0; nf < 8; ++nf) {
          float p = exp2f((s[mf][nf][reg] - mn) * SCALE_LOG2);
          s[mf][nf][reg] = p;
          rs += p;
        }
        #pragma unroll
        for (int d2 = 1; d2 < 16; d2 <<= 1) rs += __shfl_xor(rs, d2);
        l_run[mf][reg] = l_run[mf][reg] * sc + rs;
        #pragma unroll
        for (int ni = 0; ni < 4; ++ni) o[mf][ni][reg] *= sc;
      }

    // P -> LDS bf16 (per-wave private region; same-wave readback, compiler inserts waits)
    u16* pw = &plds[w * 32 * 136];
    #pragma unroll
    for (int mf = 0; mf < 2; ++mf)
      #pragma unroll
      for (int nf = 0; nf < 8; ++nf)
        #pragma unroll
        for (int reg = 0; reg < 4; ++reg)
          pw[(mf * 16 + g * 4 + reg) * 136 + nf * 16 + r16] = f2bfu(s[mf][nf][reg]);

    // O += P V
    #pragma unroll
    for (int ks = 0; ks < 4; ++ks) {
      bf16x8 pa[2];
      #pragma unroll
      for (int mf = 0; mf < 2; ++mf)
        pa[mf] = *reinterpret_cast<const bf16x8*>(&pw[(mf * 16 + r16) * 136 + ks * 32 + g * 8]);
      #pragma unroll
      for (int ni = 0; ni < 4; ++ni) {
        bf16x8 vb = *reinterpret_cast<const bf16x8*>(&vt[(ni * 16 + r16) * 136 + ks * 32 + g * 8]);
        #pragma unroll
        for (int mf = 0; mf < 2; ++mf)
          o[mf][ni] = __builtin_amdgcn_mfma_f32_16x16x32_bf16(pa[mf], vb, o[mf][ni], 0, 0, 0);
      }
    }
  }

  // normalize + write attn_out [b*4096+n*128+row][h*64+dh] bf16
  u16* orow = aout + (bs + (size_t)n * 128) * 1024 + h * 64;
  #pragma unroll
  for (int mf = 0; mf < 2; ++mf)
    #pragma unroll
    for (int ni = 0; ni < 4; ++ni)
      #pragma unroll
      for (int reg = 0; reg < 4; ++reg) {
        int row = w * 32 + mf * 16 + g * 4 + reg;
        int col = ni * 16 + r16;
        float v = o[mf][ni][reg] / l_run[mf][reg];
        orow[(size_t)row * 1024 + col] = f2bfu(v);
      }
}

extern "C" void kernel_launch(void* const* d_in, const int* in_sizes, int n_in,
                              void* d_out, int out_size, void* d_ws, size_t ws_size,
                              hipStream_t stream) {
  const float* x    = (const float*)d_in[0];
  const float* Wqkv = (const float*)d_in[1];
  const float* bqkv = (const float*)d_in[2];
  const float* Wout = (const float*)d_in[3];
  const float* bout = (const float*)d_in[4];
  float* out = (float*)d_out;

  char* ws = (char*)d_ws;
  u16* xb    = (u16*)(ws);
  u16* qkv   = (u16*)(ws + 33554432);
  u16* aoutb = (u16*)(ws + 134217728);
  u16* wqkvT = (u16*)(ws + 167772160);
  u16* woutT = (u16*)(ws + 174063616);

  cvt_x_kernel<<<4096, 256, 0, stream>>>(x, xb, 16384 * 1024 / 4);
  transpose_cvt_kernel<<<32 * 96, 256, 0, stream>>>(Wqkv, wqkvT, 1024, 3072);
  transpose_cvt_kernel<<<32 * 32, 256, 0, stream>>>(Wout, woutT, 1024, 1024);
  gemm_bt_kernel<true><<<128 * 24, 256, 0, stream>>>(xb, wqkvT, bqkv, (void*)qkv, 16384, 3072, 1024);
  attn_kernel<<<2048, 256, 0, stream>>>(qkv, aoutb);
  gemm_bt_kernel<false><<<128 * 8, 256, 0, stream>>>(aoutb, woutT, bout, (void*)out, 16384, 1024, 1024);
}

// Round 2
// 525.586 us; speedup vs baseline: 1.0429x; 1.0429x over previous
//
#include <hip/hip_runtime.h>
#include <hip/hip_bf16.h>

// LocalWindowAttention on MI355X, bf16 MFMA pipeline, head-major attention layout.
// Workspace layout (bytes):
//   x_bf16   @ 0          : 16384*1024*2 = 33,554,432
//   qkv_hm   @ 33554432   : 3 sections of [B*H=64][S=4096][64] bf16, 33,554,432 each
//   attn_out @ 134217728  : 16384*1024*2 = 33,554,432  (row-major [S][1024])
//   WqkvT    @ 167772160  : 3072*1024*2  = 6,291,456
//   WoutT    @ 174063616  : 1024*1024*2  = 2,097,152

typedef unsigned short u16;
typedef __bf16 bf16x8 __attribute__((ext_vector_type(8)));
typedef float f32x4 __attribute__((ext_vector_type(4)));

#define GLDS16(src, dst) \
  __builtin_amdgcn_global_load_lds((const __attribute__((address_space(1))) void*)(src), \
                                   (__attribute__((address_space(3))) void*)(dst), 16, 0, 0)

static __device__ __forceinline__ u16 f2bfu(float f) {
  union { __hip_bfloat16 b; u16 u; } cv;
  cv.b = __float2bfloat16(f);
  return cv.u;
}

// ---------------- x fp32 -> bf16 (vectorized) ----------------
__global__ __launch_bounds__(256) void cvt_x_kernel(const float* __restrict__ in,
                                                    u16* __restrict__ out, int n4) {
  int i = blockIdx.x * 256 + threadIdx.x;
  int stride = gridDim.x * 256;
  for (; i < n4; i += stride) {
    float4 v = reinterpret_cast<const float4*>(in)[i];
    ushort4 o;
    o.x = f2bfu(v.x); o.y = f2bfu(v.y); o.z = f2bfu(v.z); o.w = f2bfu(v.w);
    reinterpret_cast<ushort4*>(out)[i] = o;
  }
}

// ---------------- W [R][C] fp32 -> Wt [C][R] bf16 ----------------
__global__ __launch_bounds__(256) void transpose_cvt_kernel(const float* __restrict__ src,
                                                            u16* __restrict__ dst, int R, int C) {
  __shared__ float tile[32][33];
  int tilesR = R >> 5;
  int tr = blockIdx.x % tilesR;
  int tc = blockIdx.x / tilesR;
  int tx = threadIdx.x & 31, ty = threadIdx.x >> 5;  // ty 0..7
  #pragma unroll
  for (int i = 0; i < 4; ++i) {
    int r = (tr << 5) + ty + (i << 3);
    int c = (tc << 5) + tx;
    tile[ty + (i << 3)][tx] = src[(size_t)r * C + c];
  }
  __syncthreads();
  #pragma unroll
  for (int i = 0; i < 4; ++i) {
    int orow = (tc << 5) + ty + (i << 3);  // original col
    int ocol = (tr << 5) + tx;             // original row
    dst[(size_t)orow * R + ocol] = f2bfu(tile[tx][ty + (i << 3)]);
  }
}

// ---------------- m97-style 128x128 GEMM: C = A * Bt^T + bias ----------------
// A [M][K] bf16, Bt [N][K] bf16. MODE 0: fp32 row-major out. MODE 2: bf16 qkv head-major split.
template <int MODE>
__global__ __launch_bounds__(256) void gemm_bt_kernel(const u16* __restrict__ A,
                                                      const u16* __restrict__ Bt,
                                                      const float* __restrict__ bias,
                                                      void* __restrict__ Cout,
                                                      int M, int N, int K) {
  __shared__ u16 lA[128 * 32];
  __shared__ u16 lB[128 * 32];
  int bid = blockIdx.x;
  // XCD-aware bijective swizzle (grid divisible by 8)
  int nb = (bid & 7) * (gridDim.x >> 3) + (bid >> 3);
  int bm = nb & 127;  // M/128 == 128
  int bn = nb >> 7;
  int t = threadIdx.x;
  int w = t >> 6, l = t & 63, g = l >> 4, r16 = l & 15;
  int wr = w >> 1, wc = w & 1;

  f32x4 acc[4][4];
  #pragma unroll
  for (int mi = 0; mi < 4; ++mi)
    #pragma unroll
    for (int ni = 0; ni < 4; ++ni)
      acc[mi][ni] = f32x4{0.f, 0.f, 0.f, 0.f};

  const size_t arow0 = (size_t)bm * 128;
  const size_t brow0 = (size_t)bn * 128;
  int ra = t >> 2;   // 0..63 (row within half-tile)
  int ca = t & 3;    // 16B chunk within 64B row

  for (int kt = 0; kt < K; kt += 32) {
    __syncthreads();
    #pragma unroll
    for (int p = 0; p < 2; ++p) {
      GLDS16(A + (arow0 + ra + 64 * p) * K + kt + ca * 8, &lA[t * 8 + p * 2048]);
      GLDS16(Bt + (brow0 + ra + 64 * p) * K + kt + ca * 8, &lB[t * 8 + p * 2048]);
    }
    __syncthreads();
    bf16x8 af[4], bf[4];
    #pragma unroll
    for (int mi = 0; mi < 4; ++mi)
      af[mi] = *reinterpret_cast<const bf16x8*>(&lA[(wr * 64 + mi * 16 + r16) * 32 + g * 8]);
    #pragma unroll
    for (int ni = 0; ni < 4; ++ni)
      bf[ni] = *reinterpret_cast<const bf16x8*>(&lB[(wc * 64 + ni * 16 + r16) * 32 + g * 8]);
    #pragma unroll
    for (int mi = 0; mi < 4; ++mi)
      #pragma unroll
      for (int ni = 0; ni < 4; ++ni)
        acc[mi][ni] = __builtin_amdgcn_mfma_f32_16x16x32_bf16(af[mi], bf[ni], acc[mi][ni], 0, 0, 0);
  }

  #pragma unroll
  for (int ni = 0; ni < 4; ++ni) {
    int col = (bn * 128) + wc * 64 + ni * 16 + r16;
    float bv = bias[col];
    if (MODE == 0) {
      #pragma unroll
      for (int mi = 0; mi < 4; ++mi) {
        int rowb = (bm * 128) + wr * 64 + mi * 16 + g * 4;
        #pragma unroll
        for (int reg = 0; reg < 4; ++reg)
          ((float*)Cout)[(size_t)(rowb + reg) * N + col] = acc[mi][ni][reg] + bv;
      }
    } else {
      // head-major split: sec in {q,k,v}, dst [b*16+h][s][dh]
      int sec = col >> 10;
      int hh = (col >> 6) & 15;
      int dh = col & 63;
      u16* base = (u16*)Cout + (size_t)sec * 16777216;
      #pragma unroll
      for (int mi = 0; mi < 4; ++mi) {
        int rowb = (bm * 128) + wr * 64 + mi * 16 + g * 4;
        int bb = rowb >> 12;
        int ss = rowb & 4095;
        size_t dst = ((size_t)(bb * 16 + hh) * 4096 + ss) * 64 + dh;
        #pragma unroll
        for (int reg = 0; reg < 4; ++reg)
          base[dst + (size_t)reg * 64] = f2bfu(acc[mi][ni][reg] + bv);
      }
    }
  }
}

// ---------------- banded attention (head-major inputs) ----------------
// grid 2048 = (b:4, h:16, n:32); 256 threads = 4 waves, wave w owns q rows [32w,32w+32).
#define SCALE_LOG2 0.04508422002778011f  // log2(e)/32

__global__ __launch_bounds__(256) void attn_kernel(const u16* __restrict__ qh,
                                                   const u16* __restrict__ kh,
                                                   const u16* __restrict__ vh,
                                                   u16* __restrict__ aout) {
  // K tile [128 key][64 dh], elem(key,dh) at byte key*128 + ((dh*2) ^ ((key&7)<<4))
  __shared__ u16 lK[128 * 64];
  // V^T tile [64 dh][128 key], elem(dh,key) at byte dh*256 + ((key*2) ^ ((((dh&7)^(dh>>3))&7)<<4))
  __shared__ u16 vt[64 * 128];
  // P per wave [32 row][128 key], elem at byte row*256 + ((col*2) ^ ((row&15)<<4))
  __shared__ u16 plds[4 * 32 * 128];

  int bid0 = blockIdx.x;
  int bid = (bid0 & 7) * 256 + (bid0 >> 3);  // XCD swizzle: contiguous (b,h) chunk per XCD
  int n = bid & 31;
  int h = (bid >> 5) & 15;
  int b = bid >> 9;

  const int t = threadIdx.x;
  const int w = t >> 6, l = t & 63, g = l >> 4, r16 = l & 15;

  const size_t head = (size_t)(b * 16 + h) * 4096;
  const u16* qsec = qh + (head + (size_t)n * 128) * 64;

  // Q A-frags in registers (contiguous 2KB region per fragment load)
  bf16x8 qa[2][2];
  #pragma unroll
  for (int mf = 0; mf < 2; ++mf)
    #pragma unroll
    for (int ks = 0; ks < 2; ++ks)
      qa[mf][ks] = *reinterpret_cast<const bf16x8*>(
          qsec + (size_t)(w * 32 + mf * 16 + r16) * 64 + ks * 32 + g * 8);

  f32x4 o[2][4];
  #pragma unroll
  for (int mf = 0; mf < 2; ++mf)
    #pragma unroll
    for (int ni = 0; ni < 4; ++ni)
      o[mf][ni] = f32x4{0.f, 0.f, 0.f, 0.f};
  float m_run[2][4], l_run[2][4];
  #pragma unroll
  for (int mf = 0; mf < 2; ++mf)
    #pragma unroll
    for (int reg = 0; reg < 4; ++reg) { m_run[mf][reg] = -3.0e38f; l_run[mf][reg] = 0.f; }

  u16* pw = &plds[w * 4096];

  for (int d = -1; d <= 1; ++d) {
    int kblk = n + d;
    if (kblk < 0 || kblk >= 32) continue;  // block-uniform
    const u16* ksec = kh + (head + (size_t)kblk * 128) * 64;
    const u16* vsec = vh + (head + (size_t)kblk * 128) * 64;

    __syncthreads();  // previous iteration's LDS reads done

    // ---- K stage: global_load_lds, linear dest + pre-swizzled source ----
    #pragma unroll
    for (int p = 0; p < 4; ++p) {
      int o_ = p * 4096 + t * 16;          // byte offset in lK
      int key = o_ >> 7;
      int m = (o_ >> 4) & 7;
      int c = m ^ (key & 7);
      GLDS16(ksec + (size_t)key * 64 + c * 8, (char*)lK + o_);
    }
    // ---- V transpose-stage: coalesced reads, swizzled conflict-free writes ----
    #pragma unroll
    for (int p = 0; p < 4; ++p) {
      int key = (t >> 3) + 32 * p;
      int c = t & 7;
      uint4 pk = *reinterpret_cast<const uint4*>(vsec + (size_t)key * 64 + c * 8);
      const u16* pv = reinterpret_cast<const u16*>(&pk);
      #pragma unroll
      for (int j = 0; j < 8; ++j) {
        int dh = c * 8 + j;
        int byte = dh * 256 + ((key * 2) ^ (((j ^ c) & 7) << 4));
        vt[byte >> 1] = pv[j];
      }
    }
    __syncthreads();

    // ---- scores S = Q K^T ----
    f32x4 s[2][8];
    #pragma unroll
    for (int mf = 0; mf < 2; ++mf)
      #pragma unroll
      for (int nf = 0; nf < 8; ++nf)
        s[mf][nf] = f32x4{0.f, 0.f, 0.f, 0.f};
    #pragma unroll
    for (int nf = 0; nf < 8; ++nf) {
      int key = nf * 16 + r16;
      #pragma unroll
      for (int ks = 0; ks < 2; ++ks) {
        bf16x8 kf = *reinterpret_cast<const bf16x8*>(
            (char*)lK + key * 128 + ((ks * 64 + g * 16) ^ ((key & 7) << 4)));
        #pragma unroll
        for (int mf = 0; mf < 2; ++mf)
          s[mf][nf] = __builtin_amdgcn_mfma_f32_16x16x32_bf16(qa[mf][ks], kf, s[mf][nf], 0, 0, 0);
      }
    }

    // masks for +-1 blocks: d=-1 valid j>=i; d=+1 valid j<=i
    if (d != 0) {
      #pragma unroll
      for (int mf = 0; mf < 2; ++mf)
        #pragma unroll
        for (int reg = 0; reg < 4; ++reg) {
          int i = w * 32 + mf * 16 + g * 4 + reg;
          #pragma unroll
          for (int nf = 0; nf < 8; ++nf) {
            int j = nf * 16 + r16;
            bool bad = (d < 0) ? (j < i) : (j > i);
            if (bad) s[mf][nf][reg] = -3.0e38f;
          }
        }
    }

    // ---- online softmax per row (rows in 16-lane groups) ----
    #pragma unroll
    for (int mf = 0; mf < 2; ++mf)
      #pragma unroll
      for (int reg = 0; reg < 4; ++reg) {
        float bm2 = s[mf][0][reg];
        #pragma unroll
        for (int nf = 1; nf < 8; ++nf) bm2 = fmaxf(bm2, s[mf][nf][reg]);
        #pragma unroll
        for (int d2 = 1; d2 < 16; d2 <<= 1) bm2 = fmaxf(bm2, __shfl_xor(bm2, d2));
        float mo = m_run[mf][reg];
        float mn = fmaxf(mo, bm2);
        float sc = exp2f((mo - mn) * SCALE_LOG2);
        m_run[mf][reg] = mn;
        float rs = 0.f;
        #pragma unroll
        for (int nf = 0; nf < 8; ++nf) {
          float p = exp2f((s[mf][nf][reg] - mn) * SCALE_LOG2);
          s[mf][nf][reg] = p;
          rs += p;
        }
        #pragma unroll
        for (int d2 = 1; d2 < 16; d2 <<= 1) rs += __shfl_xor(rs, d2);
        l_run[mf][reg] = l_run[mf][reg] * sc + rs;
        #pragma unroll
        for (int ni = 0; ni < 4; ++ni) o[mf][ni][reg] *= sc;
      }

    // ---- P -> LDS bf16 (swizzled; per-wave private, same-wave readback) ----
    #pragma unroll
    for (int mf = 0; mf < 2; ++mf)
      #pragma unroll
      for (int nf = 0; nf < 8; ++nf)
        #pragma unroll
        for (int reg = 0; reg < 4; ++reg) {
          int row = mf * 16 + g * 4 + reg;
          int col = nf * 16 + r16;
          int byte = row * 256 + ((col * 2) ^ ((row & 15) << 4));
          pw[byte >> 1] = f2bfu(s[mf][nf][reg]);
        }

    // ---- O += P V ----
    #pragma unroll
    for (int ks = 0; ks < 4; ++ks) {
      bf16x8 pa[2];
      #pragma unroll
      for (int mf = 0; mf < 2; ++mf) {
        int row = mf * 16 + r16;
        pa[mf] = *reinterpret_cast<const bf16x8*>(
            (char*)pw + row * 256 + ((ks * 64 + g * 16) ^ ((row & 15) << 4)));
      }
      #pragma unroll
      for (int ni = 0; ni < 4; ++ni) {
        int dh = ni * 16 + r16;
        bf16x8 vb = *reinterpret_cast<const bf16x8*>(
            (char*)vt + dh * 256 + ((ks * 64 + g * 16) ^ ((((dh & 7) ^ (dh >> 3)) & 7) << 4)));
        #pragma unroll
        for (int mf = 0; mf < 2; ++mf)
          o[mf][ni] = __builtin_amdgcn_mfma_f32_16x16x32_bf16(pa[mf], vb, o[mf][ni], 0, 0, 0);
      }
    }
  }

  // normalize + write attn_out row-major [b*4096+n*128+row][h*64+dh] bf16
  u16* orow = aout + ((size_t)(b * 4096 + n * 128)) * 1024 + h * 64;
  #pragma unroll
  for (int mf = 0; mf < 2; ++mf)
    #pragma unroll
    for (int ni = 0; ni < 4; ++ni)
      #pragma unroll
      for (int reg = 0; reg < 4; ++reg) {
        int row = w * 32 + mf * 16 + g * 4 + reg;
        int col = ni * 16 + r16;
        float v = o[mf][ni][reg] / l_run[mf][reg];
        orow[(size_t)row * 1024 + col] = f2bfu(v);
      }
}

extern "C" void kernel_launch(void* const* d_in, const int* in_sizes, int n_in,
                              void* d_out, int out_size, void* d_ws, size_t ws_size,
                              hipStream_t stream) {
  const float* x    = (const float*)d_in[0];
  const float* Wqkv = (const float*)d_in[1];
  const float* bqkv = (const float*)d_in[2];
  const float* Wout = (const float*)d_in[3];
  const float* bout = (const float*)d_in[4];
  float* out = (float*)d_out;

  char* ws = (char*)d_ws;
  u16* xb     = (u16*)(ws);
  u16* qkv_hm = (u16*)(ws + 33554432);   // q_hm | k_hm | v_hm, 16777216 elems each
  u16* aoutb  = (u16*)(ws + 134217728);
  u16* wqkvT  = (u16*)(ws + 167772160);
  u16* woutT  = (u16*)(ws + 174063616);

  const u16* q_hm = qkv_hm;
  const u16* k_hm = qkv_hm + 16777216;
  const u16* v_hm = qkv_hm + 33554432;

  cvt_x_kernel<<<4096, 256, 0, stream>>>(x, xb, 16384 * 1024 / 4);
  transpose_cvt_kernel<<<32 * 96, 256, 0, stream>>>(Wqkv, wqkvT, 1024, 3072);
  transpose_cvt_kernel<<<32 * 32, 256, 0, stream>>>(Wout, woutT, 1024, 1024);
  gemm_bt_kernel<2><<<128 * 24, 256, 0, stream>>>(xb, wqkvT, bqkv, (void*)qkv_hm, 16384, 3072, 1024);
  attn_kernel<<<2048, 256, 0, stream>>>(q_hm, k_hm, v_hm, aoutb);
  gemm_bt_kernel<0><<<128 * 8, 256, 0, stream>>>(aoutb, woutT, bout, (void*)out, 16384, 1024, 1024);
}

// Round 6
// 520.976 us; speedup vs baseline: 1.0521x; 1.0088x over previous
//
#include <hip/hip_runtime.h>
#include <hip/hip_bf16.h>

// LocalWindowAttention on MI355X. R5: no tr16 anywhere. V is produced already
// transposed by the QKV GEMM epilogue (vT[head][64 dh][4096 s]); attention
// stages K and V^T via global_load_lds with XOR-swizzle, P via scatter (R1).
// Workspace layout (bytes):
//   x_bf16   @ 0          : 16384*1024*2 = 33,554,432
//   qkv_hm   @ 33554432   : q_hm | k_hm [B*H=64][S=4096][64] bf16; vT [64][64][4096]
//   attn_out @ 134217728  : 16384*1024*2 = 33,554,432  (row-major [S][1024])
//   WqkvT    @ 167772160  : 3072*1024*2  = 6,291,456
//   WoutT    @ 174063616  : 1024*1024*2  = 2,097,152

typedef unsigned short u16;
typedef __bf16 bf16x8 __attribute__((ext_vector_type(8)));
typedef float f32x4 __attribute__((ext_vector_type(4)));

#define GLDS16(src, dst) \
  __builtin_amdgcn_global_load_lds((const __attribute__((address_space(1))) void*)(src), \
                                   (__attribute__((address_space(3))) void*)(dst), 16, 0, 0)

static __device__ __forceinline__ u16 f2bfu(float f) {
  union { __hip_bfloat16 b; u16 u; } cv;
  cv.b = __float2bfloat16(f);
  return cv.u;
}

// ---------------- x fp32 -> bf16 (vectorized) ----------------
__global__ __launch_bounds__(256) void cvt_x_kernel(const float* __restrict__ in,
                                                    u16* __restrict__ out, int n4) {
  int i = blockIdx.x * 256 + threadIdx.x;
  int stride = gridDim.x * 256;
  for (; i < n4; i += stride) {
    float4 v = reinterpret_cast<const float4*>(in)[i];
    ushort4 o;
    o.x = f2bfu(v.x); o.y = f2bfu(v.y); o.z = f2bfu(v.z); o.w = f2bfu(v.w);
    reinterpret_cast<ushort4*>(out)[i] = o;
  }
}

// ---------------- W [R][C] fp32 -> Wt [C][R] bf16 ----------------
__global__ __launch_bounds__(256) void transpose_cvt_kernel(const float* __restrict__ src,
                                                            u16* __restrict__ dst, int R, int C) {
  __shared__ float tile[32][33];
  int tilesR = R >> 5;
  int tr = blockIdx.x % tilesR;
  int tc = blockIdx.x / tilesR;
  int tx = threadIdx.x & 31, ty = threadIdx.x >> 5;  // ty 0..7
  #pragma unroll
  for (int i = 0; i < 4; ++i) {
    int r = (tr << 5) + ty + (i << 3);
    int c = (tc << 5) + tx;
    tile[ty + (i << 3)][tx] = src[(size_t)r * C + c];
  }
  __syncthreads();
  #pragma unroll
  for (int i = 0; i < 4; ++i) {
    int orow = (tc << 5) + ty + (i << 3);  // original col
    int ocol = (tr << 5) + tx;             // original row
    dst[(size_t)orow * R + ocol] = f2bfu(tile[tx][ty + (i << 3)]);
  }
}

// ---------------- m97-style 128x128 GEMM: C = A * Bt^T + bias ----------------
// A [M][K] bf16, Bt [N][K] bf16. MODE 0: fp32 row-major out.
// MODE 2: bf16 qkv head-major split; q,k -> [head][s][dh], v -> TRANSPOSED [head][dh][s].
template <int MODE>
__global__ __launch_bounds__(256) void gemm_bt_kernel(const u16* __restrict__ A,
                                                      const u16* __restrict__ Bt,
                                                      const float* __restrict__ bias,
                                                      void* __restrict__ Cout,
                                                      int M, int N, int K) {
  __shared__ u16 lA[128 * 32];
  __shared__ u16 lB[128 * 32];
  int bid = blockIdx.x;
  // XCD-aware bijective swizzle (grid divisible by 8)
  int nb = (bid & 7) * (gridDim.x >> 3) + (bid >> 3);
  int bm = nb & 127;  // M/128 == 128
  int bn = nb >> 7;
  int t = threadIdx.x;
  int w = t >> 6, l = t & 63, g = l >> 4, r16 = l & 15;
  int wr = w >> 1, wc = w & 1;

  f32x4 acc[4][4];
  #pragma unroll
  for (int mi = 0; mi < 4; ++mi)
    #pragma unroll
    for (int ni = 0; ni < 4; ++ni)
      acc[mi][ni] = f32x4{0.f, 0.f, 0.f, 0.f};

  const size_t arow0 = (size_t)bm * 128;
  const size_t brow0 = (size_t)bn * 128;
  int ra = t >> 2;   // 0..63 (row within half-tile)
  int ca = t & 3;    // 16B chunk within 64B row

  for (int kt = 0; kt < K; kt += 32) {
    __syncthreads();
    #pragma unroll
    for (int p = 0; p < 2; ++p) {
      GLDS16(A + (arow0 + ra + 64 * p) * K + kt + ca * 8, &lA[t * 8 + p * 2048]);
      GLDS16(Bt + (brow0 + ra + 64 * p) * K + kt + ca * 8, &lB[t * 8 + p * 2048]);
    }
    __syncthreads();
    bf16x8 af[4], bf[4];
    #pragma unroll
    for (int mi = 0; mi < 4; ++mi)
      af[mi] = *reinterpret_cast<const bf16x8*>(&lA[(wr * 64 + mi * 16 + r16) * 32 + g * 8]);
    #pragma unroll
    for (int ni = 0; ni < 4; ++ni)
      bf[ni] = *reinterpret_cast<const bf16x8*>(&lB[(wc * 64 + ni * 16 + r16) * 32 + g * 8]);
    #pragma unroll
    for (int mi = 0; mi < 4; ++mi)
      #pragma unroll
      for (int ni = 0; ni < 4; ++ni)
        acc[mi][ni] = __builtin_amdgcn_mfma_f32_16x16x32_bf16(af[mi], bf[ni], acc[mi][ni], 0, 0, 0);
  }

  #pragma unroll
  for (int ni = 0; ni < 4; ++ni) {
    int col = (bn * 128) + wc * 64 + ni * 16 + r16;
    float bv = bias[col];
    if (MODE == 0) {
      #pragma unroll
      for (int mi = 0; mi < 4; ++mi) {
        int rowb = (bm * 128) + wr * 64 + mi * 16 + g * 4;
        #pragma unroll
        for (int reg = 0; reg < 4; ++reg)
          ((float*)Cout)[(size_t)(rowb + reg) * N + col] = acc[mi][ni][reg] + bv;
      }
    } else {
      // head-major split: sec in {q,k,v}; sec uniform across the wave (ni-level)
      int sec = col >> 10;
      int hh = (col >> 6) & 15;
      int dh = col & 63;
      #pragma unroll
      for (int mi = 0; mi < 4; ++mi) {
        int rowb = (bm * 128) + wr * 64 + mi * 16 + g * 4;
        int bb = rowb >> 12;
        int ss = rowb & 4095;
        if (sec == 2) {
          // v transposed: vT[(bb*16+hh)][dh][s], 4 consecutive s per lane
          u16* vT = (u16*)Cout + (size_t)2 * 16777216;
          ushort4 pk;
          pk.x = f2bfu(acc[mi][ni][0] + bv);
          pk.y = f2bfu(acc[mi][ni][1] + bv);
          pk.z = f2bfu(acc[mi][ni][2] + bv);
          pk.w = f2bfu(acc[mi][ni][3] + bv);
          *reinterpret_cast<ushort4*>(
              &vT[((size_t)(bb * 16 + hh) * 64 + dh) * 4096 + ss]) = pk;
        } else {
          u16* base = (u16*)Cout + (size_t)sec * 16777216;
          size_t dst = ((size_t)(bb * 16 + hh) * 4096 + ss) * 64 + dh;
          #pragma unroll
          for (int reg = 0; reg < 4; ++reg)
            base[dst + (size_t)reg * 64] = f2bfu(acc[mi][ni][reg] + bv);
        }
      }
    }
  }
}

// ---------------- banded attention (head-major q/k, transposed v) ----------------
// grid 2048 = (b:4, h:16, n:32); 256 threads = 4 waves, wave w owns q rows [32w,32w+32).
// LDS:
//  lK  [128 key][64 dh]: byte = key*128 + ((dh*2) ^ ((key&7)<<4))              (16 KB)
//  lVT [64 dh][128 key]: byte = dh*256 + ((key*2) ^ ((dh&7)<<4))               (16 KB)
//  plds per-wave P [32 q][128 key]: byte row*256 + ((col*2) ^ ((row&15)<<4))   (32 KB)
#define SCALE_LOG2 0.04508422002778011f  // log2(e)/32

__global__ __launch_bounds__(256) void attn_kernel(const u16* __restrict__ qh,
                                                   const u16* __restrict__ kh,
                                                   const u16* __restrict__ vT,
                                                   u16* __restrict__ aout) {
  __shared__ alignas(16) u16 lK[128 * 64];
  __shared__ alignas(16) u16 lVT[64 * 128];
  __shared__ alignas(16) u16 plds[4 * 32 * 128];

  int bid0 = blockIdx.x;
  int bid = (bid0 & 7) * 256 + (bid0 >> 3);  // XCD swizzle
  int n = bid & 31;
  int h = (bid >> 5) & 15;
  int b = bid >> 9;

  const int t = threadIdx.x;
  const int w = t >> 6, l = t & 63, g = l >> 4, r16 = l & 15;

  const size_t head = (size_t)(b * 16 + h) * 4096;
  const u16* qsec = qh + (head + (size_t)n * 128) * 64;

  // staging precomputes (p-invariant)
  const int kc8 = ((t & 7) ^ ((t >> 3) & 7)) * 8;  // K: source dh-chunk (u16 units)
  const int v_dh_lo = t >> 4;                      // + 16*p
  const int v_c = ((t & 15) ^ (v_dh_lo & 7)) * 8;  // V: source key-chunk (u16 units)

  // Q A-frags in registers
  bf16x8 qa[2][2];
  #pragma unroll
  for (int mf = 0; mf < 2; ++mf)
    #pragma unroll
    for (int ks = 0; ks < 2; ++ks)
      qa[mf][ks] = *reinterpret_cast<const bf16x8*>(
          qsec + (size_t)(w * 32 + mf * 16 + r16) * 64 + ks * 32 + g * 8);

  f32x4 o[2][4];
  #pragma unroll
  for (int mf = 0; mf < 2; ++mf)
    #pragma unroll
    for (int ni = 0; ni < 4; ++ni)
      o[mf][ni] = f32x4{0.f, 0.f, 0.f, 0.f};
  float m_run[2][4], l_run[2][4];
  #pragma unroll
  for (int mf = 0; mf < 2; ++mf)
    #pragma unroll
    for (int reg = 0; reg < 4; ++reg) { m_run[mf][reg] = -3.0e38f; l_run[mf][reg] = 0.f; }

  u16* pw = &plds[w * 4096];

  for (int d = -1; d <= 1; ++d) {
    int kblk = n + d;
    if (kblk < 0 || kblk >= 32) continue;  // block-uniform
    const u16* ksec = kh + (head + (size_t)kblk * 128) * 64;
    const u16* vsecT = vT + head * 64 + (size_t)kblk * 128;  // [dh][s] rows, stride 4096

    __syncthreads();  // previous iteration's LDS reads done

    // ---- K stage: linear dest + pre-swizzled source ----
    #pragma unroll
    for (int p = 0; p < 4; ++p) {
      int key = (t >> 3) + 32 * p;
      GLDS16(ksec + (size_t)key * 64 + kc8, (char*)lK + t * 16 + p * 4096);
    }
    // ---- V^T stage: linear dest + pre-swizzled source (same pattern as K) ----
    #pragma unroll
    for (int p = 0; p < 4; ++p) {
      int dh = v_dh_lo + 16 * p;
      GLDS16(vsecT + (size_t)dh * 4096 + v_c, (char*)lVT + t * 16 + p * 4096);
    }
    __syncthreads();

    // ---- scores S = Q K^T ----
    f32x4 s[2][8];
    #pragma unroll
    for (int mf = 0; mf < 2; ++mf)
      #pragma unroll
      for (int nf = 0; nf < 8; ++nf)
        s[mf][nf] = f32x4{0.f, 0.f, 0.f, 0.f};
    #pragma unroll
    for (int nf = 0; nf < 8; ++nf) {
      int key = nf * 16 + r16;
      #pragma unroll
      for (int ks = 0; ks < 2; ++ks) {
        bf16x8 kf = *reinterpret_cast<const bf16x8*>(
            (char*)lK + key * 128 + ((ks * 64 + g * 16) ^ ((key & 7) << 4)));
        #pragma unroll
        for (int mf = 0; mf < 2; ++mf)
          s[mf][nf] = __builtin_amdgcn_mfma_f32_16x16x32_bf16(qa[mf][ks], kf, s[mf][nf], 0, 0, 0);
      }
    }

    // masks for +-1 blocks: d=-1 valid j>=i; d=+1 valid j<=i
    if (d != 0) {
      #pragma unroll
      for (int mf = 0; mf < 2; ++mf)
        #pragma unroll
        for (int reg = 0; reg < 4; ++reg) {
          int i = w * 32 + mf * 16 + g * 4 + reg;
          #pragma unroll
          for (int nf = 0; nf < 8; ++nf) {
            int j = nf * 16 + r16;
            bool bad = (d < 0) ? (j < i) : (j > i);
            if (bad) s[mf][nf][reg] = -3.0e38f;
          }
        }
    }

    // ---- online softmax per row (always-rescale) ----
    #pragma unroll
    for (int mf = 0; mf < 2; ++mf)
      #pragma unroll
      for (int reg = 0; reg < 4; ++reg) {
        float bm2 = s[mf][0][reg];
        #pragma unroll
        for (int nf = 1; nf < 8; ++nf) bm2 = fmaxf(bm2, s[mf][nf][reg]);
        #pragma unroll
        for (int d2 = 1; d2 < 16; d2 <<= 1) bm2 = fmaxf(bm2, __shfl_xor(bm2, d2));
        float mo = m_run[mf][reg];
        float mn = fmaxf(mo, bm2);
        float sc = exp2f((mo - mn) * SCALE_LOG2);
        m_run[mf][reg] = mn;
        float rs = 0.f;
        #pragma unroll
        for (int nf = 0; nf < 8; ++nf) {
          float p = exp2f((s[mf][nf][reg] - mn) * SCALE_LOG2);
          s[mf][nf][reg] = p;
          rs += p;
        }
        #pragma unroll
        for (int d2 = 1; d2 < 16; d2 <<= 1) rs += __shfl_xor(rs, d2);
        l_run[mf][reg] = l_run[mf][reg] * sc + rs;
        #pragma unroll
        for (int ni = 0; ni < 4; ++ni) o[mf][ni][reg] *= sc;
      }

    // ---- P -> LDS bf16 (scatter-write; per-wave private, same-wave readback) ----
    #pragma unroll
    for (int mf = 0; mf < 2; ++mf)
      #pragma unroll
      for (int nf = 0; nf < 8; ++nf)
        #pragma unroll
        for (int reg = 0; reg < 4; ++reg) {
          int row = mf * 16 + g * 4 + reg;
          int col = nf * 16 + r16;
          int byte = row * 256 + ((col * 2) ^ ((row & 15) << 4));
          pw[byte >> 1] = f2bfu(s[mf][nf][reg]);
        }

    // ---- O += P V : both operands from swizzled b128 reads ----
    #pragma unroll
    for (int ks = 0; ks < 4; ++ks) {
      bf16x8 pa[2], vb[4];
      #pragma unroll
      for (int mf = 0; mf < 2; ++mf) {
        int row = mf * 16 + r16;
        pa[mf] = *reinterpret_cast<const bf16x8*>(
            (char*)pw + row * 256 + ((ks * 64 + g * 16) ^ ((row & 15) << 4)));
      }
      #pragma unroll
      for (int ni = 0; ni < 4; ++ni) {
        int dh = ni * 16 + r16;
        vb[ni] = *reinterpret_cast<const bf16x8*>(
            (char*)lVT + dh * 256 + ((ks * 64 + g * 16) ^ ((dh & 7) << 4)));
      }
      #pragma unroll
      for (int ni = 0; ni < 4; ++ni)
        #pragma unroll
        for (int mf = 0; mf < 2; ++mf)
          o[mf][ni] = __builtin_amdgcn_mfma_f32_16x16x32_bf16(pa[mf], vb[ni], o[mf][ni], 0, 0, 0);
    }
  }

  // normalize + write attn_out row-major [b*4096+n*128+row][h*64+dh] bf16
  u16* orow = aout + ((size_t)(b * 4096 + n * 128)) * 1024 + h * 64;
  #pragma unroll
  for (int mf = 0; mf < 2; ++mf)
    #pragma unroll
    for (int ni = 0; ni < 4; ++ni)
      #pragma unroll
      for (int reg = 0; reg < 4; ++reg) {
        int row = w * 32 + mf * 16 + g * 4 + reg;
        int col = ni * 16 + r16;
        float v = o[mf][ni][reg] / l_run[mf][reg];
        orow[(size_t)row * 1024 + col] = f2bfu(v);
      }
}

extern "C" void kernel_launch(void* const* d_in, const int* in_sizes, int n_in,
                              void* d_out, int out_size, void* d_ws, size_t ws_size,
                              hipStream_t stream) {
  const float* x    = (const float*)d_in[0];
  const float* Wqkv = (const float*)d_in[1];
  const float* bqkv = (const float*)d_in[2];
  const float* Wout = (const float*)d_in[3];
  const float* bout = (const float*)d_in[4];
  float* out = (float*)d_out;

  char* ws = (char*)d_ws;
  u16* xb     = (u16*)(ws);
  u16* qkv_hm = (u16*)(ws + 33554432);   // q_hm | k_hm | vT, 16777216 elems each
  u16* aoutb  = (u16*)(ws + 134217728);
  u16* wqkvT  = (u16*)(ws + 167772160);
  u16* woutT  = (u16*)(ws + 174063616);

  const u16* q_hm = qkv_hm;
  const u16* k_hm = qkv_hm + 16777216;
  const u16* v_T  = qkv_hm + 33554432;

  cvt_x_kernel<<<4096, 256, 0, stream>>>(x, xb, 16384 * 1024 / 4);
  transpose_cvt_kernel<<<32 * 96, 256, 0, stream>>>(Wqkv, wqkvT, 1024, 3072);
  transpose_cvt_kernel<<<32 * 32, 256, 0, stream>>>(Wout, woutT, 1024, 1024);
  gemm_bt_kernel<2><<<128 * 24, 256, 0, stream>>>(xb, wqkvT, bqkv, (void*)qkv_hm, 16384, 3072, 1024);
  attn_kernel<<<2048, 256, 0, stream>>>(q_hm, k_hm, v_T, aoutb);
  gemm_bt_kernel<0><<<128 * 8, 256, 0, stream>>>(aoutb, woutT, bout, (void*)out, 16384, 1024, 1024);
}

// Round 7
// 478.900 us; speedup vs baseline: 1.1445x; 1.0879x over previous
//
#include <hip/hip_runtime.h>
#include <hip/hip_bf16.h>

// LocalWindowAttention on MI355X. R6: GEMMs ported to 256x256/BK=64 8-wave
// deep-pipelined structure (counted vmcnt(2), 2 barriers per 64-MFMA K-tile).
// Attention identical to R5 (passing).
// Workspace layout (bytes):
//   x_bf16   @ 0          : 16384*1024*2 = 33,554,432
//   qkv_hm   @ 33554432   : q_hm | k_hm [B*H=64][S=4096][64] bf16; vT [64][64][4096]
//   attn_out @ 134217728  : 16384*1024*2 = 33,554,432  (row-major [S][1024])
//   WqkvT    @ 167772160  : 3072*1024*2  = 6,291,456
//   WoutT    @ 174063616  : 1024*1024*2  = 2,097,152

typedef unsigned short u16;
typedef __bf16 bf16x8 __attribute__((ext_vector_type(8)));
typedef float f32x4 __attribute__((ext_vector_type(4)));

#define GLDS16(src, dst) \
  __builtin_amdgcn_global_load_lds((const __attribute__((address_space(1))) void*)(src), \
                                   (__attribute__((address_space(3))) void*)(dst), 16, 0, 0)

static __device__ __forceinline__ u16 f2bfu(float f) {
  union { __hip_bfloat16 b; u16 u; } cv;
  cv.b = __float2bfloat16(f);
  return cv.u;
}

// ---------------- x fp32 -> bf16 (vectorized) ----------------
__global__ __launch_bounds__(256) void cvt_x_kernel(const float* __restrict__ in,
                                                    u16* __restrict__ out, int n4) {
  int i = blockIdx.x * 256 + threadIdx.x;
  int stride = gridDim.x * 256;
  for (; i < n4; i += stride) {
    float4 v = reinterpret_cast<const float4*>(in)[i];
    ushort4 o;
    o.x = f2bfu(v.x); o.y = f2bfu(v.y); o.z = f2bfu(v.z); o.w = f2bfu(v.w);
    reinterpret_cast<ushort4*>(out)[i] = o;
  }
}

// ---------------- W [R][C] fp32 -> Wt [C][R] bf16 ----------------
__global__ __launch_bounds__(256) void transpose_cvt_kernel(const float* __restrict__ src,
                                                            u16* __restrict__ dst, int R, int C) {
  __shared__ float tile[32][33];
  int tilesR = R >> 5;
  int tr = blockIdx.x % tilesR;
  int tc = blockIdx.x / tilesR;
  int tx = threadIdx.x & 31, ty = threadIdx.x >> 5;  // ty 0..7
  #pragma unroll
  for (int i = 0; i < 4; ++i) {
    int r = (tr << 5) + ty + (i << 3);
    int c = (tc << 5) + tx;
    tile[ty + (i << 3)][tx] = src[(size_t)r * C + c];
  }
  __syncthreads();
  #pragma unroll
  for (int i = 0; i < 4; ++i) {
    int orow = (tc << 5) + ty + (i << 3);  // original col
    int ocol = (tr << 5) + tx;             // original row
    dst[(size_t)orow * R + ocol] = f2bfu(tile[tx][ty + (i << 3)]);
  }
}

// ---------------- 256x256 BK=64 deep-pipelined GEMM: C = A * Bt^T + bias ----------------
// A [M][K] bf16, Bt [N][K] bf16, K multiple of 64, M/N multiples of 256 (M=16384).
// 512 threads = 8 waves (wm 0..1, wn 0..3); per-wave output 128x64 = acc[8][4].
// LDS per buffer: A 256x64 bf16 (32KB), B same. Double-buffered = 128 KB total.
// Frag swizzle: elem(row, kbyte) at byte row*128 + (kbyte ^ ((row&7)<<4)) -> 2-way free.
// Stage: linear dest (gload_lds) + pre-swizzled source chunk c = (t&7)^(r&7).
// Sync per K-tile kt: barrier; issue A0(kt+1); vmcnt(2) [proof: issue order
// ...A0..B1(kt), A0(kt+1) -> vmcnt(2) drains all kt halves]; barrier; 4x16 MFMA
// with A1/B0/B1(kt+1) issued between quadrants.
// MODE 0: fp32 row-major out. MODE 2: bf16 qkv head-major split (v transposed).
template <int MODE>
__global__ __launch_bounds__(512, 2) void gemm256_kernel(const u16* __restrict__ A,
                                                         const u16* __restrict__ Bt,
                                                         const float* __restrict__ bias,
                                                         void* __restrict__ Cout,
                                                         int M, int N, int K) {
  __shared__ alignas(16) u16 lds[4 * 16384];  // [A0|A1|B0|B1] buffers, 32KB each
  u16* lA = lds;
  u16* lB = lds + 2 * 16384;

  int bid = blockIdx.x;
  int nb = (bid & 7) * (gridDim.x >> 3) + (bid >> 3);  // XCD swizzle (grid % 8 == 0)
  int bm = nb & 63;   // M/256 == 64 (M = 16384)
  int bn = nb >> 6;

  const int t = threadIdx.x;
  const int wid = t >> 6, l = t & 63, g = l >> 4, r16 = l & 15;
  const int wm = wid >> 2, wn = wid & 3;

  const int arow0 = bm * 256;
  const int brow0 = bn * 256;

  // staging precompute: thread t covers rows j*64 + (t>>3), slot t&7, j=0,1
  const int st_r0 = t >> 3;          // row within half (j=0); j=1 adds 64
  const int st_m = t & 7;

  f32x4 acc[8][4];
  #pragma unroll
  for (int mi = 0; mi < 8; ++mi)
    #pragma unroll
    for (int ni = 0; ni < 4; ++ni)
      acc[mi][ni] = f32x4{0.f, 0.f, 0.f, 0.f};

  const int NT = K >> 6;

  // stage one 128-row half (16KB): 2 gload_lds per thread
  auto stage_half = [&](const u16* srcRow0, u16* ldsb) {
    #pragma unroll
    for (int j = 0; j < 2; ++j) {
      int r = j * 64 + st_r0;
      int c = st_m ^ (r & 7);
      GLDS16(srcRow0 + (size_t)r * K + c * 8, (char*)ldsb + j * 8192 + t * 16);
    }
  };

  // prologue: stage K-tile 0 (4 halves)
  stage_half(A + (size_t)arow0 * K, lA);
  stage_half(A + (size_t)(arow0 + 128) * K, lA + 8192);
  stage_half(Bt + (size_t)brow0 * K, lB);
  stage_half(Bt + (size_t)(brow0 + 128) * K, lB + 8192);

  for (int kt = 0; kt < NT; ++kt) {
    int cur = kt & 1;
    u16* curA = lA + cur * 16384;
    u16* curB = lB + cur * 16384;
    u16* nxtA = lA + (cur ^ 1) * 16384;
    u16* nxtB = lB + (cur ^ 1) * 16384;
    const u16* An = A + (size_t)arow0 * K + (kt + 1) * 64;
    const u16* Bn = Bt + (size_t)brow0 * K + (kt + 1) * 64;
    bool pf = (kt + 1 < NT);

    asm volatile("s_barrier" ::: "memory");  // all waves done reading buffer (kt-1)
    if (pf) {
      stage_half(An, nxtA);  // A0(kt+1)
      asm volatile("s_waitcnt vmcnt(2)" ::: "memory");
    } else {
      asm volatile("s_waitcnt vmcnt(0)" ::: "memory");
    }
    asm volatile("s_barrier" ::: "memory");  // kt fully staged, block-wide

    #pragma unroll
    for (int ks = 0; ks < 2; ++ks) {
      bf16x8 bf[4];
      #pragma unroll
      for (int ni = 0; ni < 4; ++ni) {
        int row = wn * 64 + ni * 16 + r16;
        bf[ni] = *reinterpret_cast<const bf16x8*>(
            (const char*)curB + row * 128 + ((ks * 64 + g * 16) ^ ((row & 7) << 4)));
      }
      #pragma unroll
      for (int mh = 0; mh < 2; ++mh) {
        bf16x8 af[4];
        #pragma unroll
        for (int m2 = 0; m2 < 4; ++m2) {
          int row = wm * 128 + (mh * 4 + m2) * 16 + r16;
          af[m2] = *reinterpret_cast<const bf16x8*>(
              (const char*)curA + row * 128 + ((ks * 64 + g * 16) ^ ((row & 7) << 4)));
        }
        if (pf && ks == 0 && mh == 0) stage_half(An + (size_t)128 * K, nxtA + 8192);  // A1'
        if (pf && ks == 0 && mh == 1) stage_half(Bn, nxtB);                            // B0'
        if (pf && ks == 1 && mh == 0) stage_half(Bn + (size_t)128 * K, nxtB + 8192);   // B1'
        __builtin_amdgcn_s_setprio(1);
        #pragma unroll
        for (int m2 = 0; m2 < 4; ++m2)
          #pragma unroll
          for (int ni = 0; ni < 4; ++ni)
            acc[mh * 4 + m2][ni] =
                __builtin_amdgcn_mfma_f32_16x16x32_bf16(af[m2], bf[ni], acc[mh * 4 + m2][ni], 0, 0, 0);
        __builtin_amdgcn_s_setprio(0);
      }
    }
  }

  // ---- epilogue ----
  #pragma unroll
  for (int ni = 0; ni < 4; ++ni) {
    int col = bn * 256 + wn * 64 + ni * 16 + r16;
    float bv = bias[col];
    if (MODE == 0) {
      #pragma unroll
      for (int mi = 0; mi < 8; ++mi) {
        int rowb = bm * 256 + wm * 128 + mi * 16 + g * 4;
        #pragma unroll
        for (int reg = 0; reg < 4; ++reg)
          ((float*)Cout)[(size_t)(rowb + reg) * N + col] = acc[mi][ni][reg] + bv;
      }
    } else {
      // head-major split: sec in {q,k,v}
      int sec = col >> 10;
      int hh = (col >> 6) & 15;
      int dh = col & 63;
      #pragma unroll
      for (int mi = 0; mi < 8; ++mi) {
        int rowb = bm * 256 + wm * 128 + mi * 16 + g * 4;
        int bb = rowb >> 12;
        int ss = rowb & 4095;
        if (sec == 2) {
          // v transposed: vT[(bb*16+hh)][dh][s], 4 consecutive s per lane
          u16* vT = (u16*)Cout + (size_t)2 * 16777216;
          ushort4 pk;
          pk.x = f2bfu(acc[mi][ni][0] + bv);
          pk.y = f2bfu(acc[mi][ni][1] + bv);
          pk.z = f2bfu(acc[mi][ni][2] + bv);
          pk.w = f2bfu(acc[mi][ni][3] + bv);
          *reinterpret_cast<ushort4*>(
              &vT[((size_t)(bb * 16 + hh) * 64 + dh) * 4096 + ss]) = pk;
        } else {
          u16* base = (u16*)Cout + (size_t)sec * 16777216;
          size_t dst = ((size_t)(bb * 16 + hh) * 4096 + ss) * 64 + dh;
          #pragma unroll
          for (int reg = 0; reg < 4; ++reg)
            base[dst + (size_t)reg * 64] = f2bfu(acc[mi][ni][reg] + bv);
        }
      }
    }
  }
}

// ---------------- banded attention (head-major q/k, transposed v) ----------------
// grid 2048 = (b:4, h:16, n:32); 256 threads = 4 waves, wave w owns q rows [32w,32w+32).
// LDS:
//  lK  [128 key][64 dh]: byte = key*128 + ((dh*2) ^ ((key&7)<<4))              (16 KB)
//  lVT [64 dh][128 key]: byte = dh*256 + ((key*2) ^ ((dh&7)<<4))               (16 KB)
//  plds per-wave P [32 q][128 key]: byte row*256 + ((col*2) ^ ((row&15)<<4))   (32 KB)
#define SCALE_LOG2 0.04508422002778011f  // log2(e)/32

__global__ __launch_bounds__(256) void attn_kernel(const u16* __restrict__ qh,
                                                   const u16* __restrict__ kh,
                                                   const u16* __restrict__ vT,
                                                   u16* __restrict__ aout) {
  __shared__ alignas(16) u16 lK[128 * 64];
  __shared__ alignas(16) u16 lVT[64 * 128];
  __shared__ alignas(16) u16 plds[4 * 32 * 128];

  int bid0 = blockIdx.x;
  int bid = (bid0 & 7) * 256 + (bid0 >> 3);  // XCD swizzle
  int n = bid & 31;
  int h = (bid >> 5) & 15;
  int b = bid >> 9;

  const int t = threadIdx.x;
  const int w = t >> 6, l = t & 63, g = l >> 4, r16 = l & 15;

  const size_t head = (size_t)(b * 16 + h) * 4096;
  const u16* qsec = qh + (head + (size_t)n * 128) * 64;

  // staging precomputes (p-invariant)
  const int kc8 = ((t & 7) ^ ((t >> 3) & 7)) * 8;  // K: source dh-chunk (u16 units)
  const int v_dh_lo = t >> 4;                      // + 16*p
  const int v_c = ((t & 15) ^ (v_dh_lo & 7)) * 8;  // V: source key-chunk (u16 units)

  // Q A-frags in registers
  bf16x8 qa[2][2];
  #pragma unroll
  for (int mf = 0; mf < 2; ++mf)
    #pragma unroll
    for (int ks = 0; ks < 2; ++ks)
      qa[mf][ks] = *reinterpret_cast<const bf16x8*>(
          qsec + (size_t)(w * 32 + mf * 16 + r16) * 64 + ks * 32 + g * 8);

  f32x4 o[2][4];
  #pragma unroll
  for (int mf = 0; mf < 2; ++mf)
    #pragma unroll
    for (int ni = 0; ni < 4; ++ni)
      o[mf][ni] = f32x4{0.f, 0.f, 0.f, 0.f};
  float m_run[2][4], l_run[2][4];
  #pragma unroll
  for (int mf = 0; mf < 2; ++mf)
    #pragma unroll
    for (int reg = 0; reg < 4; ++reg) { m_run[mf][reg] = -3.0e38f; l_run[mf][reg] = 0.f; }

  u16* pw = &plds[w * 4096];

  for (int d = -1; d <= 1; ++d) {
    int kblk = n + d;
    if (kblk < 0 || kblk >= 32) continue;  // block-uniform
    const u16* ksec = kh + (head + (size_t)kblk * 128) * 64;
    const u16* vsecT = vT + head * 64 + (size_t)kblk * 128;  // [dh][s] rows, stride 4096

    __syncthreads();  // previous iteration's LDS reads done

    // ---- K stage: linear dest + pre-swizzled source ----
    #pragma unroll
    for (int p = 0; p < 4; ++p) {
      int key = (t >> 3) + 32 * p;
      GLDS16(ksec + (size_t)key * 64 + kc8, (char*)lK + t * 16 + p * 4096);
    }
    // ---- V^T stage: linear dest + pre-swizzled source (same pattern as K) ----
    #pragma unroll
    for (int p = 0; p < 4; ++p) {
      int dh = v_dh_lo + 16 * p;
      GLDS16(vsecT + (size_t)dh * 4096 + v_c, (char*)lVT + t * 16 + p * 4096);
    }
    __syncthreads();

    // ---- scores S = Q K^T ----
    f32x4 s[2][8];
    #pragma unroll
    for (int mf = 0; mf < 2; ++mf)
      #pragma unroll
      for (int nf = 0; nf < 8; ++nf)
        s[mf][nf] = f32x4{0.f, 0.f, 0.f, 0.f};
    #pragma unroll
    for (int nf = 0; nf < 8; ++nf) {
      int key = nf * 16 + r16;
      #pragma unroll
      for (int ks = 0; ks < 2; ++ks) {
        bf16x8 kf = *reinterpret_cast<const bf16x8*>(
            (char*)lK + key * 128 + ((ks * 64 + g * 16) ^ ((key & 7) << 4)));
        #pragma unroll
        for (int mf = 0; mf < 2; ++mf)
          s[mf][nf] = __builtin_amdgcn_mfma_f32_16x16x32_bf16(qa[mf][ks], kf, s[mf][nf], 0, 0, 0);
      }
    }

    // masks for +-1 blocks: d=-1 valid j>=i; d=+1 valid j<=i
    if (d != 0) {
      #pragma unroll
      for (int mf = 0; mf < 2; ++mf)
        #pragma unroll
        for (int reg = 0; reg < 4; ++reg) {
          int i = w * 32 + mf * 16 + g * 4 + reg;
          #pragma unroll
          for (int nf = 0; nf < 8; ++nf) {
            int j = nf * 16 + r16;
            bool bad = (d < 0) ? (j < i) : (j > i);
            if (bad) s[mf][nf][reg] = -3.0e38f;
          }
        }
    }

    // ---- online softmax per row (always-rescale) ----
    #pragma unroll
    for (int mf = 0; mf < 2; ++mf)
      #pragma unroll
      for (int reg = 0; reg < 4; ++reg) {
        float bm2 = s[mf][0][reg];
        #pragma unroll
        for (int nf = 1; nf < 8; ++nf) bm2 = fmaxf(bm2, s[mf][nf][reg]);
        #pragma unroll
        for (int d2 = 1; d2 < 16; d2 <<= 1) bm2 = fmaxf(bm2, __shfl_xor(bm2, d2));
        float mo = m_run[mf][reg];
        float mn = fmaxf(mo, bm2);
        float sc = exp2f((mo - mn) * SCALE_LOG2);
        m_run[mf][reg] = mn;
        float rs = 0.f;
        #pragma unroll
        for (int nf = 0; nf < 8; ++nf) {
          float p = exp2f((s[mf][nf][reg] - mn) * SCALE_LOG2);
          s[mf][nf][reg] = p;
          rs += p;
        }
        #pragma unroll
        for (int d2 = 1; d2 < 16; d2 <<= 1) rs += __shfl_xor(rs, d2);
        l_run[mf][reg] = l_run[mf][reg] * sc + rs;
        #pragma unroll
        for (int ni = 0; ni < 4; ++ni) o[mf][ni][reg] *= sc;
      }

    // ---- P -> LDS bf16 (scatter-write; per-wave private, same-wave readback) ----
    #pragma unroll
    for (int mf = 0; mf < 2; ++mf)
      #pragma unroll
      for (int nf = 0; nf < 8; ++nf)
        #pragma unroll
        for (int reg = 0; reg < 4; ++reg) {
          int row = mf * 16 + g * 4 + reg;
          int col = nf * 16 + r16;
          int byte = row * 256 + ((col * 2) ^ ((row & 15) << 4));
          pw[byte >> 1] = f2bfu(s[mf][nf][reg]);
        }

    // ---- O += P V : both operands from swizzled b128 reads ----
    #pragma unroll
    for (int ks = 0; ks < 4; ++ks) {
      bf16x8 pa[2], vb[4];
      #pragma unroll
      for (int mf = 0; mf < 2; ++mf) {
        int row = mf * 16 + r16;
        pa[mf] = *reinterpret_cast<const bf16x8*>(
            (char*)pw + row * 256 + ((ks * 64 + g * 16) ^ ((row & 15) << 4)));
      }
      #pragma unroll
      for (int ni = 0; ni < 4; ++ni) {
        int dh = ni * 16 + r16;
        vb[ni] = *reinterpret_cast<const bf16x8*>(
            (char*)lVT + dh * 256 + ((ks * 64 + g * 16) ^ ((dh & 7) << 4)));
      }
      #pragma unroll
      for (int ni = 0; ni < 4; ++ni)
        #pragma unroll
        for (int mf = 0; mf < 2; ++mf)
          o[mf][ni] = __builtin_amdgcn_mfma_f32_16x16x32_bf16(pa[mf], vb[ni], o[mf][ni], 0, 0, 0);
    }
  }

  // normalize + write attn_out row-major [b*4096+n*128+row][h*64+dh] bf16
  u16* orow = aout + ((size_t)(b * 4096 + n * 128)) * 1024 + h * 64;
  #pragma unroll
  for (int mf = 0; mf < 2; ++mf)
    #pragma unroll
    for (int ni = 0; ni < 4; ++ni)
      #pragma unroll
      for (int reg = 0; reg < 4; ++reg) {
        int row = w * 32 + mf * 16 + g * 4 + reg;
        int col = ni * 16 + r16;
        float v = o[mf][ni][reg] / l_run[mf][reg];
        orow[(size_t)row * 1024 + col] = f2bfu(v);
      }
}

extern "C" void kernel_launch(void* const* d_in, const int* in_sizes, int n_in,
                              void* d_out, int out_size, void* d_ws, size_t ws_size,
                              hipStream_t stream) {
  const float* x    = (const float*)d_in[0];
  const float* Wqkv = (const float*)d_in[1];
  const float* bqkv = (const float*)d_in[2];
  const float* Wout = (const float*)d_in[3];
  const float* bout = (const float*)d_in[4];
  float* out = (float*)d_out;

  char* ws = (char*)d_ws;
  u16* xb     = (u16*)(ws);
  u16* qkv_hm = (u16*)(ws + 33554432);   // q_hm | k_hm | vT, 16777216 elems each
  u16* aoutb  = (u16*)(ws + 134217728);
  u16* wqkvT  = (u16*)(ws + 167772160);
  u16* woutT  = (u16*)(ws + 174063616);

  const u16* q_hm = qkv_hm;
  const u16* k_hm = qkv_hm + 16777216;
  const u16* v_T  = qkv_hm + 33554432;

  cvt_x_kernel<<<4096, 256, 0, stream>>>(x, xb, 16384 * 1024 / 4);
  transpose_cvt_kernel<<<32 * 96, 256, 0, stream>>>(Wqkv, wqkvT, 1024, 3072);
  transpose_cvt_kernel<<<32 * 32, 256, 0, stream>>>(Wout, woutT, 1024, 1024);
  gemm256_kernel<2><<<64 * 12, 512, 0, stream>>>(xb, wqkvT, bqkv, (void*)qkv_hm, 16384, 3072, 1024);
  attn_kernel<<<2048, 256, 0, stream>>>(q_hm, k_hm, v_T, aoutb);
  gemm256_kernel<0><<<64 * 4, 512, 0, stream>>>(aoutb, woutT, bout, (void*)out, 16384, 1024, 1024);
}

// Round 9
// 385.939 us; speedup vs baseline: 1.4202x; 1.2409x over previous
//
#include <hip/hip_runtime.h>
#include <hip/hip_bf16.h>

// LocalWindowAttention on MI355X. R7 resubmit (R8): attention as swapped-operand
// 32x32 MFMA flash kernel — S^T = mfma(K,Q), in-register P->PV via pack +
// lane^32 exchange, O^T = mfma(V^T, P^T), no max tracking (scale 1/32 bounds
// scores), no P LDS round-trip. GEMMs = R6 (256x256 BK=64 counted-vmcnt).
// Workspace layout (bytes):
//   x_bf16   @ 0          : 16384*1024*2 = 33,554,432
//   qkv_hm   @ 33554432   : q_hm | k_hm [B*H=64][S=4096][64] bf16; vT [64][64][4096]
//   attn_out @ 134217728  : 16384*1024*2 = 33,554,432  (row-major [S][1024])
//   WqkvT    @ 167772160  : 3072*1024*2  = 6,291,456
//   WoutT    @ 174063616  : 1024*1024*2  = 2,097,152

typedef unsigned short u16;
typedef __bf16 bf16x8 __attribute__((ext_vector_type(8)));
typedef float f32x4 __attribute__((ext_vector_type(4)));
typedef float f32x16 __attribute__((ext_vector_type(16)));

#define GLDS16(src, dst) \
  __builtin_amdgcn_global_load_lds((const __attribute__((address_space(1))) void*)(src), \
                                   (__attribute__((address_space(3))) void*)(dst), 16, 0, 0)

static __device__ __forceinline__ u16 f2bfu(float f) {
  union { __hip_bfloat16 b; u16 u; } cv;
  cv.b = __float2bfloat16(f);
  return cv.u;
}
static __device__ __forceinline__ unsigned pk2(float lo, float hi_) {
  return ((unsigned)f2bfu(hi_) << 16) | (unsigned)f2bfu(lo);
}

// ---------------- x fp32 -> bf16 (vectorized) ----------------
__global__ __launch_bounds__(256) void cvt_x_kernel(const float* __restrict__ in,
                                                    u16* __restrict__ out, int n4) {
  int i = blockIdx.x * 256 + threadIdx.x;
  int stride = gridDim.x * 256;
  for (; i < n4; i += stride) {
    float4 v = reinterpret_cast<const float4*>(in)[i];
    ushort4 o;
    o.x = f2bfu(v.x); o.y = f2bfu(v.y); o.z = f2bfu(v.z); o.w = f2bfu(v.w);
    reinterpret_cast<ushort4*>(out)[i] = o;
  }
}

// ---------------- W [R][C] fp32 -> Wt [C][R] bf16 ----------------
__global__ __launch_bounds__(256) void transpose_cvt_kernel(const float* __restrict__ src,
                                                            u16* __restrict__ dst, int R, int C) {
  __shared__ float tile[32][33];
  int tilesR = R >> 5;
  int tr = blockIdx.x % tilesR;
  int tc = blockIdx.x / tilesR;
  int tx = threadIdx.x & 31, ty = threadIdx.x >> 5;  // ty 0..7
  #pragma unroll
  for (int i = 0; i < 4; ++i) {
    int r = (tr << 5) + ty + (i << 3);
    int c = (tc << 5) + tx;
    tile[ty + (i << 3)][tx] = src[(size_t)r * C + c];
  }
  __syncthreads();
  #pragma unroll
  for (int i = 0; i < 4; ++i) {
    int orow = (tc << 5) + ty + (i << 3);  // original col
    int ocol = (tr << 5) + tx;             // original row
    dst[(size_t)orow * R + ocol] = f2bfu(tile[tx][ty + (i << 3)]);
  }
}

// ---------------- 256x256 BK=64 deep-pipelined GEMM: C = A * Bt^T + bias ----------------
// (unchanged from R6 — passing)
template <int MODE>
__global__ __launch_bounds__(512, 2) void gemm256_kernel(const u16* __restrict__ A,
                                                         const u16* __restrict__ Bt,
                                                         const float* __restrict__ bias,
                                                         void* __restrict__ Cout,
                                                         int M, int N, int K) {
  __shared__ alignas(16) u16 lds[4 * 16384];  // [A0|A1|B0|B1] buffers, 32KB each
  u16* lA = lds;
  u16* lB = lds + 2 * 16384;

  int bid = blockIdx.x;
  int nb = (bid & 7) * (gridDim.x >> 3) + (bid >> 3);  // XCD swizzle (grid % 8 == 0)
  int bm = nb & 63;   // M/256 == 64 (M = 16384)
  int bn = nb >> 6;

  const int t = threadIdx.x;
  const int wid = t >> 6, l = t & 63, g = l >> 4, r16 = l & 15;
  const int wm = wid >> 2, wn = wid & 3;

  const int arow0 = bm * 256;
  const int brow0 = bn * 256;

  const int st_r0 = t >> 3;          // row within half (j=0); j=1 adds 64
  const int st_m = t & 7;

  f32x4 acc[8][4];
  #pragma unroll
  for (int mi = 0; mi < 8; ++mi)
    #pragma unroll
    for (int ni = 0; ni < 4; ++ni)
      acc[mi][ni] = f32x4{0.f, 0.f, 0.f, 0.f};

  const int NT = K >> 6;

  auto stage_half = [&](const u16* srcRow0, u16* ldsb) {
    #pragma unroll
    for (int j = 0; j < 2; ++j) {
      int r = j * 64 + st_r0;
      int c = st_m ^ (r & 7);
      GLDS16(srcRow0 + (size_t)r * K + c * 8, (char*)ldsb + j * 8192 + t * 16);
    }
  };

  stage_half(A + (size_t)arow0 * K, lA);
  stage_half(A + (size_t)(arow0 + 128) * K, lA + 8192);
  stage_half(Bt + (size_t)brow0 * K, lB);
  stage_half(Bt + (size_t)(brow0 + 128) * K, lB + 8192);

  for (int kt = 0; kt < NT; ++kt) {
    int cur = kt & 1;
    u16* curA = lA + cur * 16384;
    u16* curB = lB + cur * 16384;
    u16* nxtA = lA + (cur ^ 1) * 16384;
    u16* nxtB = lB + (cur ^ 1) * 16384;
    const u16* An = A + (size_t)arow0 * K + (kt + 1) * 64;
    const u16* Bn = Bt + (size_t)brow0 * K + (kt + 1) * 64;
    bool pf = (kt + 1 < NT);

    asm volatile("s_barrier" ::: "memory");
    if (pf) {
      stage_half(An, nxtA);  // A0(kt+1)
      asm volatile("s_waitcnt vmcnt(2)" ::: "memory");
    } else {
      asm volatile("s_waitcnt vmcnt(0)" ::: "memory");
    }
    asm volatile("s_barrier" ::: "memory");

    #pragma unroll
    for (int ks = 0; ks < 2; ++ks) {
      bf16x8 bf[4];
      #pragma unroll
      for (int ni = 0; ni < 4; ++ni) {
        int row = wn * 64 + ni * 16 + r16;
        bf[ni] = *reinterpret_cast<const bf16x8*>(
            (const char*)curB + row * 128 + ((ks * 64 + g * 16) ^ ((row & 7) << 4)));
      }
      #pragma unroll
      for (int mh = 0; mh < 2; ++mh) {
        bf16x8 af[4];
        #pragma unroll
        for (int m2 = 0; m2 < 4; ++m2) {
          int row = wm * 128 + (mh * 4 + m2) * 16 + r16;
          af[m2] = *reinterpret_cast<const bf16x8*>(
              (const char*)curA + row * 128 + ((ks * 64 + g * 16) ^ ((row & 7) << 4)));
        }
        if (pf && ks == 0 && mh == 0) stage_half(An + (size_t)128 * K, nxtA + 8192);  // A1'
        if (pf && ks == 0 && mh == 1) stage_half(Bn, nxtB);                            // B0'
        if (pf && ks == 1 && mh == 0) stage_half(Bn + (size_t)128 * K, nxtB + 8192);   // B1'
        __builtin_amdgcn_s_setprio(1);
        #pragma unroll
        for (int m2 = 0; m2 < 4; ++m2)
          #pragma unroll
          for (int ni = 0; ni < 4; ++ni)
            acc[mh * 4 + m2][ni] =
                __builtin_amdgcn_mfma_f32_16x16x32_bf16(af[m2], bf[ni], acc[mh * 4 + m2][ni], 0, 0, 0);
        __builtin_amdgcn_s_setprio(0);
      }
    }
  }

  #pragma unroll
  for (int ni = 0; ni < 4; ++ni) {
    int col = bn * 256 + wn * 64 + ni * 16 + r16;
    float bv = bias[col];
    if (MODE == 0) {
      #pragma unroll
      for (int mi = 0; mi < 8; ++mi) {
        int rowb = bm * 256 + wm * 128 + mi * 16 + g * 4;
        #pragma unroll
        for (int reg = 0; reg < 4; ++reg)
          ((float*)Cout)[(size_t)(rowb + reg) * N + col] = acc[mi][ni][reg] + bv;
      }
    } else {
      int sec = col >> 10;
      int hh = (col >> 6) & 15;
      int dh = col & 63;
      #pragma unroll
      for (int mi = 0; mi < 8; ++mi) {
        int rowb = bm * 256 + wm * 128 + mi * 16 + g * 4;
        int bb = rowb >> 12;
        int ss = rowb & 4095;
        if (sec == 2) {
          u16* vT = (u16*)Cout + (size_t)2 * 16777216;
          ushort4 pk;
          pk.x = f2bfu(acc[mi][ni][0] + bv);
          pk.y = f2bfu(acc[mi][ni][1] + bv);
          pk.z = f2bfu(acc[mi][ni][2] + bv);
          pk.w = f2bfu(acc[mi][ni][3] + bv);
          *reinterpret_cast<ushort4*>(
              &vT[((size_t)(bb * 16 + hh) * 64 + dh) * 4096 + ss]) = pk;
        } else {
          u16* base = (u16*)Cout + (size_t)sec * 16777216;
          size_t dst = ((size_t)(bb * 16 + hh) * 4096 + ss) * 64 + dh;
          #pragma unroll
          for (int reg = 0; reg < 4; ++reg)
            base[dst + (size_t)reg * 64] = f2bfu(acc[mi][ni][reg] + bv);
        }
      }
    }
  }
}

// ---------------- banded attention: swapped-operand 32x32, in-register P ----------------
// grid 2048 = (b:4, h:16, n:32); 256 threads = 4 waves, wave w owns q rows [32w,32w+32).
// Per wave: S^T = mfma32(K, Q) -> lane col = q (l&31), rows = keys
// (r&3)+8*(r>>2)+4*hi. P = exp2(s/32*log2e) with NO max subtraction (scores
// bounded; softmax shift-invariant). P^T B-frags for PV built in-register:
// pack reg pairs to bf16x2, exchange lane^32, select. O^T = mfma32(V^T, P^T)
// -> lane col = q, rows = dh -> l-normalize in-lane.
// LDS: lK [128 key][64 dh] byte key*128 + ((dh*2)^((key&7)<<4))     (16 KB)
//      lVT [64 dh][128 key] byte dh*256 + ((key*2)^((dh&7)<<4))     (16 KB)
#define SCALE_LOG2 0.04508422002778011f  // log2(e)/32

__global__ __launch_bounds__(256) void attn_kernel(const u16* __restrict__ qh,
                                                   const u16* __restrict__ kh,
                                                   const u16* __restrict__ vT,
                                                   u16* __restrict__ aout) {
  __shared__ alignas(16) u16 lK[128 * 64];
  __shared__ alignas(16) u16 lVT[64 * 128];

  int bid0 = blockIdx.x;
  int bid = (bid0 & 7) * 256 + (bid0 >> 3);  // XCD swizzle
  int n = bid & 31;
  int h = (bid >> 5) & 15;
  int b = bid >> 9;

  const int t = threadIdx.x;
  const int w = t >> 6, l = t & 63;
  const int q32 = l & 31;   // this lane's q (column) index within the wave tile
  const int hi = l >> 5;    // lane half

  const size_t head = (size_t)(b * 16 + h) * 4096;
  const u16* qsec = qh + (head + (size_t)n * 128) * 64;

  // staging precomputes (p-invariant; layouts proven in R5/R6)
  const int kc8 = ((t & 7) ^ ((t >> 3) & 7)) * 8;
  const int v_dh_lo = t >> 4;
  const int v_c = ((t & 15) ^ (v_dh_lo & 7)) * 8;

  // Q B-frags: col=q, k = ks*16 + hi*8 + j (contiguous 16B per lane)
  bf16x8 qb[4];
  #pragma unroll
  for (int ks = 0; ks < 4; ++ks)
    qb[ks] = *reinterpret_cast<const bf16x8*>(
        qsec + (size_t)(w * 32 + q32) * 64 + ks * 16 + hi * 8);

  f32x16 acc[2];
  #pragma unroll
  for (int nf = 0; nf < 2; ++nf)
    #pragma unroll
    for (int r = 0; r < 16; ++r) acc[nf][r] = 0.f;
  float l_run = 0.f;

  for (int d = -1; d <= 1; ++d) {
    int kblk = n + d;
    if (kblk < 0 || kblk >= 32) continue;  // block-uniform
    const u16* ksec = kh + (head + (size_t)kblk * 128) * 64;
    const u16* vsecT = vT + head * 64 + (size_t)kblk * 128;

    __syncthreads();  // previous iteration's LDS reads done
    #pragma unroll
    for (int p = 0; p < 4; ++p) {
      int key = (t >> 3) + 32 * p;
      GLDS16(ksec + (size_t)key * 64 + kc8, (char*)lK + t * 16 + p * 4096);
    }
    #pragma unroll
    for (int p = 0; p < 4; ++p) {
      int dh = v_dh_lo + 16 * p;
      GLDS16(vsecT + (size_t)dh * 4096 + v_c, (char*)lVT + t * 16 + p * 4096);
    }
    __syncthreads();

    float rs = 0.f;
    #pragma unroll
    for (int kf = 0; kf < 4; ++kf) {
      const int keyrow = kf * 32 + q32;  // A-operand row for QK^T (this lane's key)
      f32x16 st;
      #pragma unroll
      for (int r = 0; r < 16; ++r) st[r] = 0.f;
      #pragma unroll
      for (int ks = 0; ks < 4; ++ks) {
        bf16x8 ka = *reinterpret_cast<const bf16x8*>(
            (char*)lK + keyrow * 128 + ((ks * 32 + hi * 16) ^ ((keyrow & 7) << 4)));
        st = __builtin_amdgcn_mfma_f32_32x32x16_bf16(ka, qb[ks], st, 0, 0, 0);
      }
      // P = exp2(s * c), masked entries -> 0. Lane holds keys kf*32+(r&3)+8*(r>>2)+4*hi
      // for its q column (q = w*32 + q32).
      float p[16];
      #pragma unroll
      for (int r = 0; r < 16; ++r) {
        float pv = exp2f(st[r] * SCALE_LOG2);
        if (d != 0) {
          int j = kf * 32 + (r & 3) + 8 * (r >> 2) + 4 * hi;
          int i = w * 32 + q32;
          bool bad = (d < 0) ? (j < i) : (j > i);
          pv = bad ? 0.f : pv;
        }
        p[r] = pv;
        rs += pv;
      }
      // pack reg pairs: block r2 holds keys {4*?+b} -> two u32 each
      unsigned gpk[8];
      #pragma unroll
      for (int r2 = 0; r2 < 4; ++r2) {
        gpk[2 * r2]     = pk2(p[4 * r2],     p[4 * r2 + 1]);
        gpk[2 * r2 + 1] = pk2(p[4 * r2 + 2], p[4 * r2 + 3]);
      }
      // build P^T B-frags per 16-key window ks2 and do PV
      #pragma unroll
      for (int ks2 = 0; ks2 < 2; ++ks2) {
        unsigned a0 = gpk[4 * ks2],     a1 = gpk[4 * ks2 + 1];  // block 2ks2   (target hi=0)
        unsigned b0 = gpk[4 * ks2 + 2], b1 = gpk[4 * ks2 + 3];  // block 2ks2+1 (target hi=1)
        unsigned xa0 = (unsigned)__shfl_xor((int)a0, 32);
        unsigned xa1 = (unsigned)__shfl_xor((int)a1, 32);
        unsigned xb0 = (unsigned)__shfl_xor((int)b0, 32);
        unsigned xb1 = (unsigned)__shfl_xor((int)b1, 32);
        union { uint4 u; bf16x8 v; } pf;
        pf.u.x = hi ? xb0 : a0;   // j=0..3 from half0's block (2ks2+hi)
        pf.u.y = hi ? xb1 : a1;
        pf.u.z = hi ? b0 : xa0;   // j=4..7 from half1's block (2ks2+hi)
        pf.u.w = hi ? b1 : xa1;
        #pragma unroll
        for (int nf = 0; nf < 2; ++nf) {
          int dh = nf * 32 + q32;  // A-operand row for PV (this lane's dh)
          bf16x8 va = *reinterpret_cast<const bf16x8*>(
              (char*)lVT + dh * 256 + ((kf * 64 + ks2 * 32 + hi * 16) ^ ((dh & 7) << 4)));
          acc[nf] = __builtin_amdgcn_mfma_f32_32x32x16_bf16(va, pf.v, acc[nf], 0, 0, 0);
        }
      }
    }
    rs += __shfl_xor(rs, 32);  // combine the two key-halves -> full row sum
    l_run += rs;
  }

  // O^T frag: col = q (in-lane), row = dh = nf*32 + 8*r2 + 4*hi + b -> 8B packed writes
  float linv = 1.0f / l_run;
  const size_t qrow = (size_t)b * 4096 + (size_t)n * 128 + w * 32 + q32;
  u16* obase = aout + qrow * 1024 + h * 64;
  #pragma unroll
  for (int nf = 0; nf < 2; ++nf)
    #pragma unroll
    for (int r2 = 0; r2 < 4; ++r2) {
      ushort4 pkk;
      pkk.x = f2bfu(acc[nf][4 * r2 + 0] * linv);
      pkk.y = f2bfu(acc[nf][4 * r2 + 1] * linv);
      pkk.z = f2bfu(acc[nf][4 * r2 + 2] * linv);
      pkk.w = f2bfu(acc[nf][4 * r2 + 3] * linv);
      *reinterpret_cast<ushort4*>(obase + nf * 32 + 8 * r2 + 4 * hi) = pkk;
    }
}

extern "C" void kernel_launch(void* const* d_in, const int* in_sizes, int n_in,
                              void* d_out, int out_size, void* d_ws, size_t ws_size,
                              hipStream_t stream) {
  const float* x    = (const float*)d_in[0];
  const float* Wqkv = (const float*)d_in[1];
  const float* bqkv = (const float*)d_in[2];
  const float* Wout = (const float*)d_in[3];
  const float* bout = (const float*)d_in[4];
  float* out = (float*)d_out;

  char* ws = (char*)d_ws;
  u16* xb     = (u16*)(ws);
  u16* qkv_hm = (u16*)(ws + 33554432);   // q_hm | k_hm | vT, 16777216 elems each
  u16* aoutb  = (u16*)(ws + 134217728);
  u16* wqkvT  = (u16*)(ws + 167772160);
  u16* woutT  = (u16*)(ws + 174063616);

  const u16* q_hm = qkv_hm;
  const u16* k_hm = qkv_hm + 16777216;
  const u16* v_T  = qkv_hm + 33554432;

  cvt_x_kernel<<<4096, 256, 0, stream>>>(x, xb, 16384 * 1024 / 4);
  transpose_cvt_kernel<<<32 * 96, 256, 0, stream>>>(Wqkv, wqkvT, 1024, 3072);
  transpose_cvt_kernel<<<32 * 32, 256, 0, stream>>>(Wout, woutT, 1024, 1024);
  gemm256_kernel<2><<<64 * 12, 512, 0, stream>>>(xb, wqkvT, bqkv, (void*)qkv_hm, 16384, 3072, 1024);
  attn_kernel<<<2048, 256, 0, stream>>>(q_hm, k_hm, v_T, aoutb);
  gemm256_kernel<0><<<64 * 4, 512, 0, stream>>>(aoutb, woutT, bout, (void*)out, 16384, 1024, 1024);
}